// Round 1
// baseline (1852.402 us; speedup 1.0000x reference)
//
#include <hip/hip_runtime.h>
#include <hip/hip_bf16.h>

typedef unsigned int u32;
typedef unsigned short u16;

#define BATCH 256
#define TSTEPS 300
#define N_IN 2312
#define N_H 800
#define N_OUT 10
#define KW 74                 // bitmask words per row (73 data + 1 zero pad)
#define KPAD (KW * 32)        // 2368
#define MTOT (BATCH * TSTEPS) // 76800

#define BM 128
#define BN 160
#define BK 64
#define KSTEPS (KPAD / BK)    // 37

typedef __attribute__((ext_vector_type(8))) short bf16x8;
typedef __attribute__((ext_vector_type(4))) float f32x4;

static inline size_t alignup(size_t x) { return (x + 255) & ~(size_t)255; }

// ---------------- init: zero spike counters ----------------
__global__ void init_k(u32* cnts) {
    if (threadIdx.x < 4) cnts[threadIdx.x] = 0;
}

// ---------------- split w1 into bf16 hi + lo, zero-padded K ----------------
__global__ void prep_w(const float* __restrict__ w1,
                       __hip_bfloat16* __restrict__ Wh,
                       __hip_bfloat16* __restrict__ Wm) {
    int idx = blockIdx.x * 256 + threadIdx.x;
    if (idx >= N_H * KPAD) return;
    int n = idx / KPAD, k = idx - n * KPAD;
    float w = (k < N_IN) ? w1[(size_t)n * N_IN + k] : 0.0f;
    __hip_bfloat16 h = __float2bfloat16(w);
    float hf = __bfloat162float(h);
    __hip_bfloat16 m = __float2bfloat16(w - hf);
    Wh[idx] = h;
    Wm[idx] = m;
}

// ---------------- compact X (B,N_IN,T) fp32 -> bitmask XB[m=b*T+t][KW] ----------------
__global__ __launch_bounds__(256) void prep_x(const float* __restrict__ X,
                                              u32* __restrict__ XB,
                                              u32* __restrict__ cnts) {
    int b = blockIdx.x;       // 0..255
    int tc = blockIdx.y;      // 0..4 (t chunks of 64)
    int t0 = tc * 64;
    int nrows = min(64, TSTEPS - t0);
    __shared__ u32 bits[64][76];
    int tid = threadIdx.x;
    int tl = tid & 63;        // local t
    int wg = tid >> 6;        // word group 0..3
    int t = t0 + tl;
    bool tvalid = (tl < nrows);
    u32 pc = 0;
    for (int j = 0; j < 19; ++j) {
        int w = wg + 4 * j;
        if (w >= KW) break;   // uniform per wave (wg == wave id)
        u32 reg = 0;
        if (w < 73 && tvalid) {
            int ibase = w * 32;
            int nb = min(32, N_IN - ibase);
            const float* xp = X + ((size_t)b * N_IN + ibase) * TSTEPS + t;
            for (int bit = 0; bit < nb; ++bit) {
                float v = xp[(size_t)bit * TSTEPS];   // coalesced across lanes (t)
                reg |= (v > 0.5f) ? (1u << bit) : 0u;
            }
        }
        pc += __popc(reg);
        bits[tl][w] = reg;
    }
    // wave-reduce popcount, one atomic per wave
    for (int off = 32; off; off >>= 1) pc += __shfl_down(pc, off);
    if ((tid & 63) == 0 && pc) atomicAdd(cnts + 0, pc);
    __syncthreads();
    // coalesced contiguous write-out
    int total = nrows * KW;
    u32* outp = XB + (size_t)(b * TSTEPS + t0) * KW;
    for (int idx = tid; idx < total; idx += 256) {
        int r = idx / KW, w = idx - r * KW;
        outp[idx] = bits[r][w];
    }
}

// ---------------- GEMM: C1[m][h] = sum_i A[m][i] * w1[h][i], split-bf16 MFMA ----------------
__global__ __launch_bounds__(256) void gemm_k(const u32* __restrict__ XB,
                                              const __hip_bfloat16* __restrict__ Wh,
                                              const __hip_bfloat16* __restrict__ Wm,
                                              float* __restrict__ C1,
                                              int m_base) {
    int nb = blockIdx.x;      // 0..4
    int mb = blockIdx.y;
    int m0 = mb * BM, n0 = nb * BN;
    __shared__ u16 Ab[BM][72];    // 64 k + pad 8
    __shared__ u16 Bh[BN][72];
    __shared__ u16 Bm[BN][72];
    int tid = threadIdx.x;
    int lane = tid & 63, wave = tid >> 6;
    int wm = wave >> 1, wn = wave & 1;   // 2x2 wave grid, wave tile 64x80
    f32x4 acc[4][5] = {};

    for (int ks = 0; ks < KSTEPS; ++ks) {
        int k0 = ks * BK;
        // ---- stage A from bitmask: row = tid/2, half-word = tid&1 ----
        {
            int row = tid >> 1, half = tid & 1;
            u32 wv = XB[(size_t)(m_base + m0 + row) * KW + (k0 >> 5) + half];
            u32 u[8];
#pragma unroll
            for (int j = 0; j < 8; ++j) {
                u32 lo = ((wv >> (2 * j)) & 1u) ? 0x3F80u : 0u;
                u32 hi = ((wv >> (2 * j + 1)) & 1u) ? 0x3F80u : 0u;
                u[j] = lo | (hi << 16);
            }
            uint4 v0; v0.x = u[0]; v0.y = u[1]; v0.z = u[2]; v0.w = u[3];
            uint4 v1; v1.x = u[4]; v1.y = u[5]; v1.z = u[6]; v1.w = u[7];
            *reinterpret_cast<uint4*>(&Ab[row][half * 32]) = v0;
            *reinterpret_cast<uint4*>(&Ab[row][half * 32 + 8]) = v1;
        }
        // ---- stage B (hi and lo parts), coalesced 16B loads ----
        for (int it = 0; it < 5; ++it) {
            int idx = it * 256 + tid;          // 0..1279
            int row = idx >> 3, kq = idx & 7;  // 8 x 16B per row = 64 k
            const uint4* sh = reinterpret_cast<const uint4*>(
                Wh + (size_t)(n0 + row) * KPAD + k0 + kq * 8);
            *reinterpret_cast<uint4*>(&Bh[row][kq * 8]) = *sh;
            const uint4* sm = reinterpret_cast<const uint4*>(
                Wm + (size_t)(n0 + row) * KPAD + k0 + kq * 8);
            *reinterpret_cast<uint4*>(&Bm[row][kq * 8]) = *sm;
        }
        __syncthreads();
        // ---- MFMA ----
#pragma unroll
        for (int kk = 0; kk < 2; ++kk) {
            int kb = kk * 32 + (lane >> 4) * 8;
            bf16x8 af[4];
#pragma unroll
            for (int mi = 0; mi < 4; ++mi)
                af[mi] = *reinterpret_cast<const bf16x8*>(&Ab[wm * 64 + mi * 16 + (lane & 15)][kb]);
#pragma unroll
            for (int ni = 0; ni < 5; ++ni) {
                bf16x8 bh = *reinterpret_cast<const bf16x8*>(&Bh[wn * 80 + ni * 16 + (lane & 15)][kb]);
                bf16x8 bl = *reinterpret_cast<const bf16x8*>(&Bm[wn * 80 + ni * 16 + (lane & 15)][kb]);
#pragma unroll
                for (int mi = 0; mi < 4; ++mi) {
                    acc[mi][ni] = __builtin_amdgcn_mfma_f32_16x16x32_bf16(af[mi], bh, acc[mi][ni], 0, 0, 0);
                    acc[mi][ni] = __builtin_amdgcn_mfma_f32_16x16x32_bf16(af[mi], bl, acc[mi][ni], 0, 0, 0);
                }
            }
        }
        __syncthreads();
    }
    // ---- epilogue: C/D layout col=lane&15, row=(lane>>4)*4+j ----
#pragma unroll
    for (int mi = 0; mi < 4; ++mi)
#pragma unroll
        for (int ni = 0; ni < 5; ++ni) {
            int col = n0 + wn * 80 + ni * 16 + (lane & 15);
            int rowb = m0 + wm * 64 + mi * 16 + ((lane >> 4) << 2);
#pragma unroll
            for (int j = 0; j < 4; ++j)
                C1[(size_t)(rowb + j) * N_H + col] = acc[mi][ni][j];
        }
}

// ---------------- sequential scan over T in (B x N_H) space ----------------
__global__ __launch_bounds__(256) void scan_k(const float* __restrict__ C1,
                                              const float* __restrict__ w2,
                                              float* __restrict__ out,
                                              u32* __restrict__ cnts,
                                              int b0) {
    const float dm = (float)0.95122942450071400910;   // exp(-1/20)
    const float dsn = (float)0.81873075307798185867;  // exp(-1/5)
    int bl = blockIdx.x;
    int b = b0 + bl;
    int tid = threadIdx.x;
    int lane = tid & 63, wave = tid >> 6;
    __shared__ float w2s[N_OUT * N_H];
    __shared__ float part[2][4][12];
    for (int i = tid; i < N_OUT * N_H; i += 256) w2s[i] = w2[i];

    float M1[4] = {0, 0, 0, 0}, S1[4] = {0, 0, 0, 0}, sav1[4] = {1, 1, 1, 1};
    float vm2[4] = {0, 0, 0, 0}, vs2[4] = {0, 0, 0, 0};
    float sav2 = 1.0f, outt = (float)TSTEPS, outu = 0.0f;
    u32 c1loc = 0, c2loc = 0;

    const float* cbase = C1 + (size_t)bl * TSTEPS * N_H;
    float ccur[4], cnext[4];
#pragma unroll
    for (int r = 0; r < 4; ++r) {
        int h = tid + 256 * r;
        ccur[r] = (h < N_H) ? cbase[h] : 0.0f;
    }
    __syncthreads();

    for (int t = 0; t < TSTEPS; ++t) {
        if (t + 1 < TSTEPS) {
#pragma unroll
            for (int r = 0; r < 4; ++r) {
                int h = tid + 256 * r;
                cnext[r] = (h < N_H) ? cbase[(size_t)(t + 1) * N_H + h] : 0.0f;
            }
        }
        float po[10];
#pragma unroll
        for (int o = 0; o < 10; ++o) po[o] = 0.0f;
#pragma unroll
        for (int r = 0; r < 4; ++r) {
            int h = tid + 256 * r;
            if (h < N_H) {
                float c = ccur[r];
                M1[r] = dm * M1[r] + c;
                S1[r] = dsn * S1[r] + c;
                float u1 = sav1[r] * (M1[r] - S1[r]);
                float spk = (u1 - 1.0f > 0.0f) ? 1.0f : 0.0f;
                sav1[r] = sav1[r] * (1.0f - spk);
                c1loc += (u32)spk;
                vm2[r] = dm * vm2[r] + spk;
                vs2[r] = dsn * vs2[r] + spk;
                float d = vm2[r] - vs2[r];
#pragma unroll
                for (int o = 0; o < 10; ++o) po[o] += d * w2s[o * N_H + h];
            }
        }
#pragma unroll
        for (int o = 0; o < 10; ++o) {
            float v = po[o];
            v += __shfl_down(v, 32); v += __shfl_down(v, 16); v += __shfl_down(v, 8);
            v += __shfl_down(v, 4);  v += __shfl_down(v, 2);  v += __shfl_down(v, 1);
            po[o] = v;
        }
        int pb = t & 1;
        if (lane == 0) {
#pragma unroll
            for (int o = 0; o < 10; ++o) part[pb][wave][o] = po[o];
        }
        __syncthreads();
        if (tid < 10) {
            float s = part[pb][0][tid] + part[pb][1][tid] + part[pb][2][tid] + part[pb][3][tid];
            float u2 = sav2 * s;
            float spk2 = (u2 - 1.0f > 0.0f) ? 1.0f : 0.0f;
            sav2 *= (1.0f - spk2);
            outt += spk2 * ((float)t - (float)TSTEPS);
            outu += spk2 * u2;
            c2loc += (u32)spk2;
        }
#pragma unroll
        for (int r = 0; r < 4; ++r) ccur[r] = cnext[r];
    }
    if (tid < 10) {
        out[b * 10 + tid] = outt;
        out[BATCH * 10 + b * 10 + tid] = outu;
        if (c2loc) atomicAdd(cnts + 2, c2loc);
    }
    for (int off = 32; off; off >>= 1) c1loc += __shfl_down(c1loc, off);
    if (lane == 0 && c1loc) atomicAdd(cnts + 1, c1loc);
}

// ---------------- finalize sum_sp ----------------
__global__ void fin_k(const u32* cnts, float* out) {
    if (threadIdx.x == 0) {
        out[2 * BATCH * 10 + 0] = (float)cnts[0];
        out[2 * BATCH * 10 + 1] = (float)cnts[1];
        out[2 * BATCH * 10 + 2] = (float)cnts[2];
    }
}

extern "C" void kernel_launch(void* const* d_in, const int* in_sizes, int n_in,
                              void* d_out, int out_size, void* d_ws, size_t ws_size,
                              hipStream_t stream) {
    (void)in_sizes; (void)n_in; (void)out_size;
    const float* X  = (const float*)d_in[0];
    const float* w1 = (const float*)d_in[1];
    const float* w2 = (const float*)d_in[2];
    float* out = (float*)d_out;
    char* ws = (char*)d_ws;

    const size_t XB_BYTES = (size_t)MTOT * KW * 4;       // 22.7 MB
    const size_t W_BYTES  = (size_t)N_H * KPAD * 2;      // 3.79 MB each

    // choose batch chunking so C1 fits in workspace
    int nch = 1;
    for (; nch <= 8; nch *= 2) {
        size_t c1b = (size_t)(MTOT / nch) * N_H * 4;
        size_t tot = alignup(c1b) + alignup(XB_BYTES) + 2 * alignup(W_BYTES) + 256;
        if (tot <= ws_size) break;
    }
    if (nch > 8) nch = 8;

    size_t off = 0;
    float* C1 = (float*)(ws + off); off += alignup((size_t)(MTOT / nch) * N_H * 4);
    u32* XB = (u32*)(ws + off);     off += alignup(XB_BYTES);
    __hip_bfloat16* Wh = (__hip_bfloat16*)(ws + off); off += alignup(W_BYTES);
    __hip_bfloat16* Wm = (__hip_bfloat16*)(ws + off); off += alignup(W_BYTES);
    u32* cnts = (u32*)(ws + off);

    init_k<<<1, 64, 0, stream>>>(cnts);
    prep_w<<<(N_H * KPAD) / 256, 256, 0, stream>>>(w1, Wh, Wm);
    prep_x<<<dim3(BATCH, 5), 256, 0, stream>>>(X, XB, cnts);

    int bchunk = BATCH / nch;
    for (int c = 0; c < nch; ++c) {
        int mbase = c * bchunk * TSTEPS;
        gemm_k<<<dim3(5, (bchunk * TSTEPS) / BM), 256, 0, stream>>>(XB, Wh, Wm, C1, mbase);
        scan_k<<<bchunk, 256, 0, stream>>>(C1, w2, out, cnts, c * bchunk);
    }
    fin_k<<<1, 64, 0, stream>>>(cnts, out);
}

// Round 2
// 1096.309 us; speedup vs baseline: 1.6897x; 1.6897x over previous
//
#include <hip/hip_runtime.h>
#include <hip/hip_bf16.h>

typedef unsigned int u32;
typedef unsigned short u16;

#define BATCH 256
#define TSTEPS 300
#define N_IN 2312
#define N_H 800
#define N_OUT 10
#define KW 74                  // bitmask words per row (73 data + 1 zero pad)
#define KREAL 2368             // padded real K
#define KP2 4736               // interleaved K' = 2*KREAL
#define KSTEPS2 74             // KP2 / 64
#define MTOT (BATCH * TSTEPS)  // 76800
#define ROWB 9472              // bytes per K' row (4736 * 2)

#define BM 128
#define BN 160

typedef __attribute__((ext_vector_type(8))) short bf16x8;
typedef __attribute__((ext_vector_type(4))) float f32x4;

static inline size_t alignup(size_t x) { return (x + 255) & ~(size_t)255; }

__device__ __forceinline__ void gl_lds16(const void* g, void* l) {
    __builtin_amdgcn_global_load_lds(
        (const __attribute__((address_space(1))) unsigned int*)g,
        (__attribute__((address_space(3))) unsigned int*)l,
        16, 0, 0);
}

// ---------------- init: zero spike counters ----------------
__global__ void init_k(u32* cnts) {
    if (threadIdx.x < 4) cnts[threadIdx.x] = 0;
}

// ---------------- w1 -> Wc[800][4736] interleaved (hi,lo) bf16 pairs ----------------
__global__ __launch_bounds__(256) void prep_w(const float* __restrict__ w1,
                                              u32* __restrict__ Wc) {
    int idx = blockIdx.x * 256 + threadIdx.x;
    if (idx >= N_H * KREAL) return;
    int h = idx / KREAL, k = idx - h * KREAL;
    float w = (k < N_IN) ? w1[(size_t)h * N_IN + k] : 0.0f;
    __hip_bfloat16 hb = __float2bfloat16(w);
    float hf = __bfloat162float(hb);
    __hip_bfloat16 lb = __float2bfloat16(w - hf);
    u32 val = (u32)(*(u16*)&hb) | ((u32)(*(u16*)&lb) << 16);
    Wc[(size_t)h * KREAL + k] = val;
}

// ---------------- X (B,N_IN,T) fp32 -> A' bf16 [m][4736] (bit duplicated), + popcount ----------------
__global__ __launch_bounds__(256) void prep_x(const float* __restrict__ X,
                                              u16* __restrict__ Aexp,
                                              u32* __restrict__ cnts,
                                              int b0) {
    int bl = blockIdx.x;
    int b = b0 + bl;
    int tc = blockIdx.y;      // 0..4 (t chunks of 64)
    int t0 = tc * 64;
    int nrows = min(64, TSTEPS - t0);
    __shared__ u32 bits[64][76];
    int tid = threadIdx.x;
    int tl = tid & 63;        // local t
    int wg = tid >> 6;        // word group 0..3 (== wave)
    int t = t0 + tl;
    bool tvalid = (tl < nrows);
    u32 pc = 0;
    for (int j = 0; j < 19; ++j) {
        int w = wg + 4 * j;
        if (w >= KW) break;   // uniform per wave
        u32 reg = 0;
        if (w < 73 && tvalid) {
            int ibase = w * 32;
            int nb = min(32, N_IN - ibase);
            const float* xp = X + ((size_t)b * N_IN + ibase) * TSTEPS + t;
            for (int bit = 0; bit < nb; ++bit) {
                float v = xp[(size_t)bit * TSTEPS];   // coalesced across lanes (t)
                reg |= (v > 0.5f) ? (1u << bit) : 0u;
            }
        }
        pc += __popc(reg);
        bits[tl][w] = reg;
    }
    for (int off = 32; off; off >>= 1) pc += __shfl_down(pc, off);
    if ((tid & 63) == 0 && pc) atomicAdd(cnts + 0, pc);
    __syncthreads();
    // expand to A' rows m = bl*300 + t0 + r  (chunk-local), 592 x 16B chunks per row
    int total = nrows * 592;
    for (int idx = tid; idx < total; idx += 256) {
        int r = idx / 592, c = idx - r * 592;
        u32 wv = bits[r][c >> 3];
        int sh = (c & 7) * 4;
        uint4 v;
        v.x = ((wv >> sh) & 1u)       ? 0x3F803F80u : 0u;
        v.y = ((wv >> (sh + 1)) & 1u) ? 0x3F803F80u : 0u;
        v.z = ((wv >> (sh + 2)) & 1u) ? 0x3F803F80u : 0u;
        v.w = ((wv >> (sh + 3)) & 1u) ? 0x3F803F80u : 0u;
        *reinterpret_cast<uint4*>((char*)Aexp + (size_t)(bl * TSTEPS + t0 + r) * ROWB + (size_t)c * 16) = v;
    }
}

// ---------------- GEMM: C1[m][h] = sum_{k'} A'[m][k'] * Wc[h][k'], m97-style ----------------
__global__ __launch_bounds__(256, 4) void gemm_k(const u16* __restrict__ Aexp,
                                                 const u16* __restrict__ Wc,
                                                 float* __restrict__ C1,
                                                 int nwg) {
    // bijective XCD-chunked swizzle: consecutive logical ids land on one XCD,
    // and logical runs of 5 share an A-panel (nb fastest).
    int d = blockIdx.y * 5 + blockIdx.x;
    int xcd = d & 7, jj = d >> 3;
    int q = nwg >> 3, r = nwg & 7;
    int lid = (xcd < r ? xcd * (q + 1) : r * (q + 1) + (xcd - r) * q) + jj;
    int mb = lid / 5, nb = lid - mb * 5;
    int m0 = mb * BM, n0 = nb * BN;

    __shared__ __align__(16) u16 As[BM * 64];   // 16 KB, rows of 128B, XOR-swizzled chunks
    __shared__ __align__(16) u16 Bs[BN * 64];   // 20 KB

    int tid = threadIdx.x, lane = tid & 63, w = tid >> 6;
    int wm = w >> 1, wn = w & 1;                // 2x2 wave grid, wave tile 64x80

    // staging source pointers (pre-swizzled global chunks -> linear LDS dest)
    const char* srcA[4];
    const char* srcB[5];
#pragma unroll
    for (int i = 0; i < 4; ++i) {
        int slot = w * 4096 + i * 1024 + lane * 16;
        int row = slot >> 7, c = (slot >> 4) & 7;
        srcA[i] = (const char*)Aexp + (size_t)(m0 + row) * ROWB + (size_t)((c ^ (row & 7)) << 4);
    }
#pragma unroll
    for (int i = 0; i < 5; ++i) {
        int slot = w * 5120 + i * 1024 + lane * 16;
        int row = slot >> 7, c = (slot >> 4) & 7;
        srcB[i] = (const char*)Wc + (size_t)(n0 + row) * ROWB + (size_t)((c ^ (row & 7)) << 4);
    }
    char* ldsA = (char*)As + w * 4096;
    char* ldsB = (char*)Bs + w * 5120;

    f32x4 acc[4][5] = {};

    for (int ks = 0; ks < KSTEPS2; ++ks) {
#pragma unroll
        for (int i = 0; i < 4; ++i) { gl_lds16(srcA[i], ldsA + i * 1024); srcA[i] += 128; }
#pragma unroll
        for (int i = 0; i < 5; ++i) { gl_lds16(srcB[i], ldsB + i * 1024); srcB[i] += 128; }
        __syncthreads();   // compiler drains vmcnt before barrier
#pragma unroll
        for (int kk = 0; kk < 2; ++kk) {
            bf16x8 af[4];
#pragma unroll
            for (int mi = 0; mi < 4; ++mi) {
                int rr = wm * 64 + mi * 16 + (lane & 15);
                af[mi] = *reinterpret_cast<const bf16x8*>(
                    &As[(rr << 6) + ((((kk << 2) + (lane >> 4)) ^ (rr & 7)) << 3)]);
            }
#pragma unroll
            for (int ni = 0; ni < 5; ++ni) {
                int rr = wn * 80 + ni * 16 + (lane & 15);
                bf16x8 bf = *reinterpret_cast<const bf16x8*>(
                    &Bs[(rr << 6) + ((((kk << 2) + (lane >> 4)) ^ (rr & 7)) << 3)]);
#pragma unroll
                for (int mi = 0; mi < 4; ++mi)
                    acc[mi][ni] = __builtin_amdgcn_mfma_f32_16x16x32_bf16(af[mi], bf, acc[mi][ni], 0, 0, 0);
            }
        }
        __syncthreads();
    }
    // epilogue: C/D layout col=lane&15, row=(lane>>4)*4+j
#pragma unroll
    for (int mi = 0; mi < 4; ++mi)
#pragma unroll
        for (int ni = 0; ni < 5; ++ni) {
            int col = n0 + wn * 80 + ni * 16 + (lane & 15);
            int rowb = m0 + wm * 64 + mi * 16 + ((lane >> 4) << 2);
#pragma unroll
            for (int j = 0; j < 4; ++j)
                C1[(size_t)(rowb + j) * N_H + col] = acc[mi][ni][j];
        }
}

// ---------------- layer-1: first-spike time per (b,h); barrier-free, prefetch depth 4 ----------------
__global__ __launch_bounds__(256) void spike1_k(const float* __restrict__ C1,
                                                u16* __restrict__ T1,
                                                u32* __restrict__ cnts,
                                                int b0) {
    const float dm = 0.95122942450071400910f;   // exp(-1/20)
    const float ds = 0.81873075307798185867f;   // exp(-1/5)
    int bl = blockIdx.x, b = b0 + bl, tid = threadIdx.x;
    const float* cbase = C1 + (size_t)bl * TSTEPS * N_H;
    bool h3ok = (tid < N_H - 768);
    float M[4] = {0, 0, 0, 0}, S[4] = {0, 0, 0, 0};
    int t1v[4] = {TSTEPS, TSTEPS, TSTEPS, TSTEPS};

    auto ld = [&](float* dst, int tt) {
        if (tt < TSTEPS) {
            const float* p = cbase + (size_t)tt * N_H;
            dst[0] = p[tid]; dst[1] = p[tid + 256]; dst[2] = p[tid + 512];
            dst[3] = h3ok ? p[tid + 768] : 0.0f;
        } else { dst[0] = dst[1] = dst[2] = dst[3] = 0.0f; }
    };
    auto step = [&](const float* cc, int t) {
#pragma unroll
        for (int r = 0; r < 4; ++r) {
            M[r] = dm * M[r] + cc[r];
            S[r] = ds * S[r] + cc[r];
            float u = M[r] - S[r];
            if (u > 1.0f && t < t1v[r]) t1v[r] = t;
        }
    };

    float c0[4], c1_[4], c2_[4], c3_[4];
    ld(c0, 0); ld(c1_, 1); ld(c2_, 2); ld(c3_, 3);
    for (int t = 0; t < TSTEPS; t += 4) {
        float n0[4], n1[4], n2[4], n3[4];
        ld(n0, t + 4); ld(n1, t + 5); ld(n2, t + 6); ld(n3, t + 7);
        step(c0, t); step(c1_, t + 1); step(c2_, t + 2); step(c3_, t + 3);
#pragma unroll
        for (int r = 0; r < 4; ++r) { c0[r] = n0[r]; c1_[r] = n1[r]; c2_[r] = n2[r]; c3_[r] = n3[r]; }
    }

    u16* tp = T1 + (size_t)b * N_H;
    tp[tid] = (u16)t1v[0];
    tp[tid + 256] = (u16)t1v[1];
    tp[tid + 512] = (u16)t1v[2];
    if (h3ok) tp[tid + 768] = (u16)t1v[3];

    u32 cnt = (u32)(t1v[0] < TSTEPS) + (u32)(t1v[1] < TSTEPS) + (u32)(t1v[2] < TSTEPS)
            + (u32)(h3ok && t1v[3] < TSTEPS);
    for (int off = 32; off; off >>= 1) cnt += __shfl_down(cnt, off);
    if ((tid & 63) == 0 && cnt) atomicAdd(cnts + 1, cnt);
}

// ---------------- layer-2: gather-by-spike-time + 10-lane recursion ----------------
__global__ __launch_bounds__(320) void out_k(const u16* __restrict__ T1,
                                             const float* __restrict__ w2,
                                             float* __restrict__ out,
                                             u32* __restrict__ cnts) {
    const float dm = 0.95122942450071400910f;
    const float ds = 0.81873075307798185867f;
    int b = blockIdx.x, tid = threadIdx.x;
    __shared__ float w2s[N_OUT * N_H];   // 32 KB
    __shared__ u16 t1s[N_H];
    __shared__ float Rs[TSTEPS][N_OUT];  // 12 KB
    for (int i = tid; i < N_OUT * N_H; i += 320) w2s[i] = w2[i];
    for (int i = tid; i < N_H; i += 320) t1s[i] = T1[(size_t)b * N_H + i];
    __syncthreads();
    if (tid < TSTEPS) {
        float R[N_OUT];
#pragma unroll
        for (int o = 0; o < N_OUT; ++o) R[o] = 0.0f;
        for (int h = 0; h < N_H; ++h) {
            if ((int)t1s[h] == tid) {
#pragma unroll
                for (int o = 0; o < N_OUT; ++o) R[o] += w2s[o * N_H + h];
            }
        }
#pragma unroll
        for (int o = 0; o < N_OUT; ++o) Rs[tid][o] = R[o];
    }
    __syncthreads();
    if (tid < N_OUT) {
        float vm = 0.0f, vs = 0.0f, sav = 1.0f, ot = (float)TSTEPS, ou = 0.0f;
        u32 c2 = 0;
        for (int t = 0; t < TSTEPS; ++t) {
            float rr = Rs[t][tid];
            vm = dm * vm + rr;
            vs = ds * vs + rr;
            float u2 = sav * (vm - vs);
            float spk = (u2 - 1.0f > 0.0f) ? 1.0f : 0.0f;
            sav *= (1.0f - spk);
            ot += spk * ((float)t - (float)TSTEPS);
            ou += spk * u2;
            c2 += (u32)spk;
        }
        out[b * N_OUT + tid] = ot;
        out[BATCH * N_OUT + b * N_OUT + tid] = ou;
        if (c2) atomicAdd(cnts + 2, c2);
    }
}

// ---------------- finalize sum_sp ----------------
__global__ void fin_k(const u32* cnts, float* out) {
    if (threadIdx.x == 0) {
        out[2 * BATCH * N_OUT + 0] = (float)cnts[0];
        out[2 * BATCH * N_OUT + 1] = (float)cnts[1];
        out[2 * BATCH * N_OUT + 2] = (float)cnts[2];
    }
}

extern "C" void kernel_launch(void* const* d_in, const int* in_sizes, int n_in,
                              void* d_out, int out_size, void* d_ws, size_t ws_size,
                              hipStream_t stream) {
    (void)in_sizes; (void)n_in; (void)out_size;
    const float* X  = (const float*)d_in[0];
    const float* w1 = (const float*)d_in[1];
    const float* w2 = (const float*)d_in[2];
    float* out = (float*)d_out;
    char* ws = (char*)d_ws;

    const size_t WC_BYTES = (size_t)N_H * KP2 * 2;   // 7.58 MB
    const size_t T1_BYTES = (size_t)BATCH * N_H * 2; // 410 KB

    // choose batch chunking so A' + C1 fit in workspace
    int nch = 1;
    for (; nch <= 8; nch *= 2) {
        size_t ab  = (size_t)(MTOT / nch) * ROWB;
        size_t c1b = (size_t)(MTOT / nch) * N_H * 4;
        size_t tot = alignup(ab) + alignup(c1b) + alignup(WC_BYTES) + alignup(T1_BYTES) + 256;
        if (tot <= ws_size) break;
    }
    if (nch > 8) nch = 8;
    int bchunk = BATCH / nch;
    int mcount = bchunk * TSTEPS;

    size_t off = 0;
    u16* Aexp = (u16*)(ws + off); off += alignup((size_t)mcount * ROWB);
    float* C1 = (float*)(ws + off); off += alignup((size_t)mcount * N_H * 4);
    u32* Wc   = (u32*)(ws + off);   off += alignup(WC_BYTES);
    u16* T1   = (u16*)(ws + off);   off += alignup(T1_BYTES);
    u32* cnts = (u32*)(ws + off);

    init_k<<<1, 64, 0, stream>>>(cnts);
    prep_w<<<(N_H * KREAL) / 256, 256, 0, stream>>>(w1, Wc);

    int nwg = 5 * (mcount / BM);
    for (int c = 0; c < nch; ++c) {
        int b0 = c * bchunk;
        prep_x<<<dim3(bchunk, 5), 256, 0, stream>>>(X, Aexp, cnts, b0);
        gemm_k<<<dim3(5, mcount / BM), 256, 0, stream>>>(Aexp, (const u16*)Wc, C1, nwg);
        spike1_k<<<bchunk, 256, 0, stream>>>(C1, T1, cnts, b0);
    }
    out_k<<<BATCH, 320, 0, stream>>>(T1, w2, out, cnts);
    fin_k<<<1, 64, 0, stream>>>(cnts, out);
}

// Round 3
// 857.410 us; speedup vs baseline: 2.1605x; 1.2786x over previous
//
#include <hip/hip_runtime.h>
#include <hip/hip_bf16.h>

typedef unsigned int u32;
typedef unsigned short u16;

#define BATCH 256
#define TSTEPS 300
#define N_IN 2312
#define N_H 800
#define N_OUT 10
#define KW 74                  // bitmask words per row (73 data + 1 zero pad)
#define KREAL 2368             // padded real K (= KW*32)
#define KSTEPS 74              // K-steps of 64 k' (= 32 real k = 1 word)
#define MTOT (BATCH * TSTEPS)  // 76800
#define ROWB 9472              // bytes per Wc row (4736 bf16)

#define BM 128
#define BN 160

typedef __attribute__((ext_vector_type(8))) short bf16x8;
typedef __attribute__((ext_vector_type(4))) float f32x4;

static inline size_t alignup(size_t x) { return (x + 255) & ~(size_t)255; }

__device__ __forceinline__ void gl_lds16(const void* g, void* l) {
    __builtin_amdgcn_global_load_lds(
        (const __attribute__((address_space(1))) unsigned int*)g,
        (__attribute__((address_space(3))) unsigned int*)l,
        16, 0, 0);
}

// ---------------- init: zero spike counters ----------------
__global__ void init_k(u32* cnts) {
    if (threadIdx.x < 4) cnts[threadIdx.x] = 0;
}

// ---------------- w1 -> Wc[800][2368 real k] interleaved (hi,lo) bf16 pairs ----------------
__global__ __launch_bounds__(256) void prep_w(const float* __restrict__ w1,
                                              u32* __restrict__ Wc) {
    int idx = blockIdx.x * 256 + threadIdx.x;
    if (idx >= N_H * KREAL) return;
    int h = idx / KREAL, k = idx - h * KREAL;
    float w = (k < N_IN) ? w1[(size_t)h * N_IN + k] : 0.0f;
    __hip_bfloat16 hb = __float2bfloat16(w);
    float hf = __bfloat162float(hb);
    __hip_bfloat16 lb = __float2bfloat16(w - hf);
    u32 val = (u32)(*(u16*)&hb) | ((u32)(*(u16*)&lb) << 16);
    Wc[(size_t)h * KREAL + k] = val;
}

// ---------------- X (B,N_IN,T) fp32 -> bitmask XB[m=bl*T+t][KW], + popcount ----------------
__global__ __launch_bounds__(256) void prep_x(const float* __restrict__ X,
                                              u32* __restrict__ XB,
                                              u32* __restrict__ cnts,
                                              int b0) {
    int bl = blockIdx.x;
    int b = b0 + bl;
    int tc = blockIdx.y;      // 0..4 (t chunks of 64)
    int t0 = tc * 64;
    int nrows = min(64, TSTEPS - t0);
    __shared__ u32 bits[64][76];
    int tid = threadIdx.x;
    int tl = tid & 63;        // local t
    int wg = tid >> 6;        // word group 0..3 (== wave)
    int t = t0 + tl;
    bool tvalid = (tl < nrows);
    u32 pc = 0;
    for (int j = 0; j < 19; ++j) {
        int w = wg + 4 * j;
        if (w >= KW) break;   // uniform per wave
        u32 reg = 0;
        if (w < 73 && tvalid) {
            int ibase = w * 32;
            int nb = min(32, N_IN - ibase);
            const float* xp = X + ((size_t)b * N_IN + ibase) * TSTEPS + t;
            for (int bit = 0; bit < nb; ++bit) {
                float v = xp[(size_t)bit * TSTEPS];   // coalesced across lanes (t)
                reg |= (v > 0.5f) ? (1u << bit) : 0u;
            }
        }
        pc += __popc(reg);
        bits[tl][w] = reg;
    }
    for (int off = 32; off; off >>= 1) pc += __shfl_down(pc, off);
    if ((tid & 63) == 0 && pc) atomicAdd(cnts + 0, pc);
    __syncthreads();
    int total = nrows * KW;
    u32* outp = XB + (size_t)(bl * TSTEPS + t0) * KW;
    for (int idx = tid; idx < total; idx += 256) {
        int r = idx / KW, w = idx - r * KW;
        outp[idx] = bits[r][w];
    }
}

// ---------------- GEMM: C1[m][h] = sum_k' A'[m][k'] * Wc[h][k'] ----------------
// A' expanded in registers from bitmask; B double-buffered via global_load_lds,
// one barrier per K-step (T3 minimal 2-phase).
__global__ __launch_bounds__(256, 4) void gemm_k(const u32* __restrict__ XB,
                                                 const u16* __restrict__ Wc,
                                                 float* __restrict__ C1,
                                                 int nwg, int mblocks) {
    // bijective XCD-chunked swizzle, n-major: consecutive lids share the Wc panel
    int d = blockIdx.y * 5 + blockIdx.x;
    int xcd = d & 7, jj = d >> 3;
    int q = nwg >> 3, r = nwg & 7;
    int lid = (xcd < r ? xcd * (q + 1) : r * (q + 1) + (xcd - r) * q) + jj;
    int nb = lid / mblocks, mb = lid - nb * mblocks;
    int m0 = mb * BM, n0 = nb * BN;

    __shared__ __align__(16) u16 Bs[2][BN * 64];   // 2 x 20 KB

    int tid = threadIdx.x, lane = tid & 63, w = tid >> 6;
    int wm = w >> 1, wn = w & 1;                   // 2x2 wave grid, wave tile 64x80

    // B staging sources (pre-swizzled global chunks -> linear LDS dest)
    const char* srcB[5];
#pragma unroll
    for (int i = 0; i < 5; ++i) {
        int slot = w * 5120 + i * 1024 + lane * 16;
        int row = slot >> 7, c = (slot >> 4) & 7;
        srcB[i] = (const char*)Wc + (size_t)(n0 + row) * ROWB + (size_t)((c ^ (row & 7)) << 4);
    }
    char* ldsB = (char*)&Bs[0][0] + w * 5120;

    // A bitmask row pointers: rows r0 + {0,16,32,48}
    int r0 = wm * 64 + (lane & 15);
    const u32* pAm0 = XB + (size_t)(m0 + r0) * KW;
    const u32* pAm1 = pAm0 + 16 * KW;
    const u32* pAm2 = pAm0 + 32 * KW;
    const u32* pAm3 = pAm0 + 48 * KW;
    int sh0 = (lane >> 4) * 4;

    f32x4 acc[4][5] = {};

    // prologue: stage ks=0 into buf 0
#pragma unroll
    for (int i = 0; i < 5; ++i) { gl_lds16(srcB[i], ldsB + i * 1024); srcB[i] += 128; }
    __syncthreads();

    for (int ks = 0; ks < KSTEPS; ++ks) {
        int buf = ks & 1;
        if (ks < KSTEPS - 1) {
            char* dst = ldsB + (buf ^ 1) * 20480;
#pragma unroll
            for (int i = 0; i < 5; ++i) { gl_lds16(srcB[i], dst + i * 1024); srcB[i] += 128; }
        }
        u32 wv0 = pAm0[ks], wv1 = pAm1[ks], wv2 = pAm2[ks], wv3 = pAm3[ks];
        const u16* bsb = &Bs[buf][0];
#pragma unroll
        for (int kk = 0; kk < 2; ++kk) {
            u32 wv[4] = {wv0, wv1, wv2, wv3};
            bf16x8 af[4];
#pragma unroll
            for (int mi = 0; mi < 4; ++mi) {
                u32 nib = wv[mi] >> (kk * 16 + sh0);
                uint4 ax;
                ax.x = (nib & 1u) ? 0x3F803F80u : 0u;
                ax.y = (nib & 2u) ? 0x3F803F80u : 0u;
                ax.z = (nib & 4u) ? 0x3F803F80u : 0u;
                ax.w = (nib & 8u) ? 0x3F803F80u : 0u;
                af[mi] = *reinterpret_cast<bf16x8*>(&ax);
            }
            __builtin_amdgcn_s_setprio(1);
#pragma unroll
            for (int ni = 0; ni < 5; ++ni) {
                int rr = wn * 80 + ni * 16 + (lane & 15);
                bf16x8 bf = *reinterpret_cast<const bf16x8*>(
                    &bsb[(rr << 6) + ((((kk << 2) + (lane >> 4)) ^ (rr & 7)) << 3)]);
#pragma unroll
                for (int mi = 0; mi < 4; ++mi)
                    acc[mi][ni] = __builtin_amdgcn_mfma_f32_16x16x32_bf16(af[mi], bf, acc[mi][ni], 0, 0, 0);
            }
            __builtin_amdgcn_s_setprio(0);
        }
        __syncthreads();
    }

    // epilogue: C/D layout col=lane&15, row=(lane>>4)*4+j
#pragma unroll
    for (int mi = 0; mi < 4; ++mi)
#pragma unroll
        for (int ni = 0; ni < 5; ++ni) {
            int col = n0 + wn * 80 + ni * 16 + (lane & 15);
            int rowb = m0 + wm * 64 + mi * 16 + ((lane >> 4) << 2);
#pragma unroll
            for (int j = 0; j < 4; ++j)
                C1[(size_t)(rowb + j) * N_H + col] = acc[mi][ni][j];
        }
}

// ---------------- layer-1: first-spike time per (b,h); barrier-free, prefetch depth 4 ----------------
__global__ __launch_bounds__(256) void spike1_k(const float* __restrict__ C1,
                                                u16* __restrict__ T1,
                                                u32* __restrict__ cnts,
                                                int b0) {
    const float dm = 0.95122942450071400910f;   // exp(-1/20)
    const float ds = 0.81873075307798185867f;   // exp(-1/5)
    int bl = blockIdx.x, b = b0 + bl, tid = threadIdx.x;
    const float* cbase = C1 + (size_t)bl * TSTEPS * N_H;
    bool h3ok = (tid < N_H - 768);
    float M[4] = {0, 0, 0, 0}, S[4] = {0, 0, 0, 0};
    int t1v[4] = {TSTEPS, TSTEPS, TSTEPS, TSTEPS};

    auto ld = [&](float* dst, int tt) {
        if (tt < TSTEPS) {
            const float* p = cbase + (size_t)tt * N_H;
            dst[0] = p[tid]; dst[1] = p[tid + 256]; dst[2] = p[tid + 512];
            dst[3] = h3ok ? p[tid + 768] : 0.0f;
        } else { dst[0] = dst[1] = dst[2] = dst[3] = 0.0f; }
    };
    auto step = [&](const float* cc, int t) {
#pragma unroll
        for (int r = 0; r < 4; ++r) {
            M[r] = dm * M[r] + cc[r];
            S[r] = ds * S[r] + cc[r];
            float u = M[r] - S[r];
            if (u > 1.0f && t < t1v[r]) t1v[r] = t;
        }
    };

    float c0[4], c1_[4], c2_[4], c3_[4];
    ld(c0, 0); ld(c1_, 1); ld(c2_, 2); ld(c3_, 3);
    for (int t = 0; t < TSTEPS; t += 4) {
        float n0[4], n1[4], n2[4], n3[4];
        ld(n0, t + 4); ld(n1, t + 5); ld(n2, t + 6); ld(n3, t + 7);
        step(c0, t); step(c1_, t + 1); step(c2_, t + 2); step(c3_, t + 3);
#pragma unroll
        for (int r = 0; r < 4; ++r) { c0[r] = n0[r]; c1_[r] = n1[r]; c2_[r] = n2[r]; c3_[r] = n3[r]; }
    }

    u16* tp = T1 + (size_t)b * N_H;
    tp[tid] = (u16)t1v[0];
    tp[tid + 256] = (u16)t1v[1];
    tp[tid + 512] = (u16)t1v[2];
    if (h3ok) tp[tid + 768] = (u16)t1v[3];

    u32 cnt = (u32)(t1v[0] < TSTEPS) + (u32)(t1v[1] < TSTEPS) + (u32)(t1v[2] < TSTEPS)
            + (u32)(h3ok && t1v[3] < TSTEPS);
    for (int off = 32; off; off >>= 1) cnt += __shfl_down(cnt, off);
    if ((tid & 63) == 0 && cnt) atomicAdd(cnts + 1, cnt);
}

// ---------------- layer-2: gather-by-spike-time + 10-lane recursion ----------------
__global__ __launch_bounds__(320) void out_k(const u16* __restrict__ T1,
                                             const float* __restrict__ w2,
                                             float* __restrict__ out,
                                             u32* __restrict__ cnts) {
    const float dm = 0.95122942450071400910f;
    const float ds = 0.81873075307798185867f;
    int b = blockIdx.x, tid = threadIdx.x;
    __shared__ float w2s[N_OUT * N_H];   // 32 KB
    __shared__ u16 t1s[N_H];
    __shared__ float Rs[TSTEPS][N_OUT];  // 12 KB
    for (int i = tid; i < N_OUT * N_H; i += 320) w2s[i] = w2[i];
    for (int i = tid; i < N_H; i += 320) t1s[i] = T1[(size_t)b * N_H + i];
    __syncthreads();
    if (tid < TSTEPS) {
        float R[N_OUT];
#pragma unroll
        for (int o = 0; o < N_OUT; ++o) R[o] = 0.0f;
        for (int h = 0; h < N_H; ++h) {
            if ((int)t1s[h] == tid) {
#pragma unroll
                for (int o = 0; o < N_OUT; ++o) R[o] += w2s[o * N_H + h];
            }
        }
#pragma unroll
        for (int o = 0; o < N_OUT; ++o) Rs[tid][o] = R[o];
    }
    __syncthreads();
    if (tid < N_OUT) {
        float vm = 0.0f, vs = 0.0f, sav = 1.0f, ot = (float)TSTEPS, ou = 0.0f;
        u32 c2 = 0;
        for (int t = 0; t < TSTEPS; ++t) {
            float rr = Rs[t][tid];
            vm = dm * vm + rr;
            vs = ds * vs + rr;
            float u2 = sav * (vm - vs);
            float spk = (u2 - 1.0f > 0.0f) ? 1.0f : 0.0f;
            sav *= (1.0f - spk);
            ot += spk * ((float)t - (float)TSTEPS);
            ou += spk * u2;
            c2 += (u32)spk;
        }
        out[b * N_OUT + tid] = ot;
        out[BATCH * N_OUT + b * N_OUT + tid] = ou;
        if (c2) atomicAdd(cnts + 2, c2);
    }
}

// ---------------- finalize sum_sp ----------------
__global__ void fin_k(const u32* cnts, float* out) {
    if (threadIdx.x == 0) {
        out[2 * BATCH * N_OUT + 0] = (float)cnts[0];
        out[2 * BATCH * N_OUT + 1] = (float)cnts[1];
        out[2 * BATCH * N_OUT + 2] = (float)cnts[2];
    }
}

extern "C" void kernel_launch(void* const* d_in, const int* in_sizes, int n_in,
                              void* d_out, int out_size, void* d_ws, size_t ws_size,
                              hipStream_t stream) {
    (void)in_sizes; (void)n_in; (void)out_size;
    const float* X  = (const float*)d_in[0];
    const float* w1 = (const float*)d_in[1];
    const float* w2 = (const float*)d_in[2];
    float* out = (float*)d_out;
    char* ws = (char*)d_ws;

    const size_t WC_BYTES = (size_t)N_H * KREAL * 4;  // 7.58 MB
    const size_t T1_BYTES = (size_t)BATCH * N_H * 2;  // 410 KB

    // choose batch chunking so XB + C1 fit in workspace
    int nch = 1;
    for (; nch <= 8; nch *= 2) {
        size_t xbb = (size_t)(MTOT / nch) * KW * 4;
        size_t c1b = (size_t)(MTOT / nch) * N_H * 4;
        size_t tot = alignup(xbb) + alignup(c1b) + alignup(WC_BYTES) + alignup(T1_BYTES) + 256;
        if (tot <= ws_size) break;
    }
    if (nch > 8) nch = 8;
    int bchunk = BATCH / nch;
    int mcount = bchunk * TSTEPS;
    int mblocks = mcount / BM;
    int nwg = 5 * mblocks;

    size_t off = 0;
    u32* XB   = (u32*)(ws + off);   off += alignup((size_t)mcount * KW * 4);
    float* C1 = (float*)(ws + off); off += alignup((size_t)mcount * N_H * 4);
    u32* Wc   = (u32*)(ws + off);   off += alignup(WC_BYTES);
    u16* T1   = (u16*)(ws + off);   off += alignup(T1_BYTES);
    u32* cnts = (u32*)(ws + off);

    init_k<<<1, 64, 0, stream>>>(cnts);
    prep_w<<<(N_H * KREAL) / 256, 256, 0, stream>>>(w1, Wc);

    for (int c = 0; c < nch; ++c) {
        int b0 = c * bchunk;
        prep_x<<<dim3(bchunk, 5), 256, 0, stream>>>(X, XB, cnts, b0);
        gemm_k<<<dim3(5, mblocks), 256, 0, stream>>>(XB, (const u16*)Wc, C1, nwg, mblocks);
        spike1_k<<<bchunk, 256, 0, stream>>>(C1, T1, cnts, b0);
    }
    out_k<<<BATCH, 320, 0, stream>>>(T1, w2, out, cnts);
    fin_k<<<1, 64, 0, stream>>>(cnts, out);
}